// Round 11
// baseline (49.036 us; speedup 1.0000x reference)
//
#include <hip/hip_runtime.h>
#include <stdint.h>

// VQ-VAE quantization: B=131072 rows of z (D=64) vs N_E=1024 codes.
// Outputs (flat f32): z_q [131072*64] | loss [1] | idx [131072] | var(idx,ddof=1) [1]
//
// R11: barrier-free self-paced waves + max occupancy.
//  - Waves split the CODEBOOK (16 tiles each) with PRIVATE LDS regions and a
//    private see-quarter -> no inter-wave synchronization in the main loop.
//  - Per-wave double-buffered 2-tile phases, counted vmcnt(4), dynamic loop.
//  - Block = 64 rows (r=4 subtile reuse: 8 MFMAs per staged frag pair),
//    grid 2048, LDS 38KB -> 4 blocks/CU = 16 independent waves/CU.
//  - Single __syncthreads before the R1-style cross-wave skey epilogue.
// key = (float_bits(0.5+||e||^2-2z.e) & ~1023) | code ; unsigned min == argmin.

typedef __attribute__((ext_vector_type(8))) __bf16 bf16x8;
typedef __attribute__((ext_vector_type(4))) float f32x4;

#define OUT_LOSS 8388608
#define OUT_IDX  8388609
#define OUT_VAR  8519681

// workspace layout (bytes)
#define WS_LOSS  0          // float[2048] per-block loss partials
#define WS_S1    8192       // int[2048] sum(idx)
#define WS_S2    16384      // int[2048] sum(idx^2)
#define WS_EFRAG 24576      // bf16x8[64 tiles * 2 ksteps * 64 lanes] = 128 KB
#define WS_EE    155648     // float[1024] ||e||^2 + 0.5 (4 KB)

__device__ __forceinline__ void gld_lds16(const void* g, void* l) {
  __builtin_amdgcn_global_load_lds(
      (const __attribute__((address_space(1))) unsigned*)g,
      (__attribute__((address_space(3))) unsigned*)l, 16, 0, 0);
}

// ---- K0: prep codebook fragments -----------------------------------------
// A-frag for mfma_f32_16x16x32_bf16: lane l holds code row (t*16 + (l&15)),
// k = kstep*32 + (l>>4)*8 + i. Values are -2*e.
__global__ void vq_prep(const float* __restrict__ emb, char* __restrict__ ws) {
  bf16x8* efrag = (bf16x8*)(ws + WS_EFRAG);
  float* eeoff = (float*)(ws + WS_EE);
  const int t = blockIdx.x;    // tile 0..63
  const int l = threadIdx.x;   // 0..63
  const int n = t * 16 + (l & 15);
  const int kb0 = (l >> 4) * 8;
  const float* er = emb + n * 64;
  for (int j = 0; j < 2; ++j) {
    const int kb = j * 32 + kb0;
    bf16x8 h;
#pragma unroll
    for (int i = 0; i < 8; ++i) h[i] = (__bf16)(-2.0f * er[kb + i]);
    efrag[(t * 2 + j) * 64 + l] = h;
  }
  if (l < 16) {
    const float* e2 = emb + (t * 16 + l) * 64;
    float s = 0.f;
#pragma unroll
    for (int d = 0; d < 64; ++d) s += e2[d] * e2[d];
    eeoff[t * 16 + l] = s + 0.5f;
  }
}

// ---- K1: distances + argmin + fused epilogue ------------------------------
// 2048 blocks x 256 thr (4 waves). Block rows = 64 (shared by all waves);
// wave w owns code tiles w*16 .. w*16+15 in a private LDS pipeline.
__global__ void __launch_bounds__(256) vq_main(
    const float* __restrict__ z, const float* __restrict__ emb,
    float* __restrict__ out, char* __restrict__ ws) {
  __shared__ char smfrag[2][4][4096];   // [buf][wave][2 tiles]
  __shared__ float see[1024];           // ||e||^2+0.5; wave w uses [w*256,+256)
  __shared__ unsigned skey[4][64];      // per-wave per-row keys
  __shared__ float szz[64];             // ||z_row||^2
  __shared__ float sL[4];
  __shared__ int sA[4], sB[4];

  const int tid = threadIdx.x;
  const int wave = tid >> 6, lane = tid & 63;
  const int lr = lane & 15, ksl = lane >> 4;
  const int k0 = ksl * 8;
  const int row_base = blockIdx.x * 64;

  // wave w stages phase p (2 tiles = 4 KB) of ITS codes into buf b (private)
#define STAGE(p, b)                                                            \
  {                                                                            \
    _Pragma("unroll")                                                          \
    for (int i_ = 0; i_ < 4; ++i_)                                             \
      gld_lds16(ws + WS_EFRAG + (size_t)(wave * 16 + (p) * 2) * 2048           \
                    + i_ * 1024 + lane * 16,                                   \
                smfrag[b][wave] + i_ * 1024);                                  \
  }

  // z loads FIRST (drained together with see+S0 by the first vmcnt(4))
  f32x4 zr[16];
#pragma unroll
  for (int r = 0; r < 4; ++r) {
    const float* zp = z + (size_t)(row_base + r * 16 + lr) * 64;
    zr[r * 4 + 0] = *(const f32x4*)(zp + k0);
    zr[r * 4 + 1] = *(const f32x4*)(zp + k0 + 4);
    zr[r * 4 + 2] = *(const f32x4*)(zp + 32 + k0);
    zr[r * 4 + 3] = *(const f32x4*)(zp + 32 + k0 + 4);
  }

  // private staging: see quarter (oldest), then phases 0,1
  gld_lds16(ws + WS_EE + wave * 1024 + lane * 16, (char*)see + wave * 1024);
  STAGE(0, 0);
  STAGE(1, 1);

  // convert z to bf16 B-fragments (col = lane&15, k = ksl*8 + i per half)
  bf16x8 zf[4][2];
#pragma unroll
  for (int r = 0; r < 4; ++r) {
#pragma unroll
    for (int i = 0; i < 4; ++i) {
      zf[r][0][i] = (__bf16)zr[r * 4 + 0][i]; zf[r][0][4 + i] = (__bf16)zr[r * 4 + 1][i];
      zf[r][1][i] = (__bf16)zr[r * 4 + 2][i]; zf[r][1][4 + i] = (__bf16)zr[r * 4 + 3][i];
    }
  }
  // ||z_row||^2 -> szz (wave 0 only; consumed after the epilogue barrier)
  if (wave == 0) {
#pragma unroll
    for (int r = 0; r < 4; ++r) {
      float s = 0.f;
#pragma unroll
      for (int i = 0; i < 4; ++i)
        s += zr[r * 4 + 0][i] * zr[r * 4 + 0][i] + zr[r * 4 + 1][i] * zr[r * 4 + 1][i]
           + zr[r * 4 + 2][i] * zr[r * 4 + 2][i] + zr[r * 4 + 3][i] * zr[r * 4 + 3][i];
      s += __shfl_xor(s, 16, 64);
      s += __shfl_xor(s, 32, 64);
      if (ksl == 0) szz[r * 16 + lr] = s;
    }
  }

  unsigned rk[4];
#pragma unroll
  for (int r = 0; r < 4; ++r) rk[r] = 0xFFFFFFFFu;
  const unsigned kj0 = (unsigned)(ksl * 4), kj1 = kj0 + 1, kj2 = kj0 + 2, kj3 = kj0 + 3;

  // self-paced pipeline: no barriers; vmcnt counts are per-wave.
  for (int ph = 0; ph < 8; ++ph) {
    if (ph < 7) { asm volatile("s_waitcnt vmcnt(4)" ::: "memory"); }
    else        { asm volatile("s_waitcnt vmcnt(0)" ::: "memory"); }
    __builtin_amdgcn_sched_barrier(0);
    const bf16x8* sf = (const bf16x8*)(smfrag[ph & 1][wave]);
    __builtin_amdgcn_s_setprio(1);
#pragma unroll
    for (int t2 = 0; t2 < 2; ++t2) {
      const int g = wave * 16 + ph * 2 + t2;          // global code tile
      bf16x8 e0 = sf[(t2 * 2 + 0) * 64 + lane];       // conflict-free b128
      bf16x8 e1 = sf[(t2 * 2 + 1) * 64 + lane];
      const f32x4 ee = *(const f32x4*)(see + g * 16 + ksl * 4);
      const unsigned g16 = (unsigned)(g * 16);
#pragma unroll
      for (int r = 0; r < 4; ++r) {                   // 4 independent chains
        f32x4 a = __builtin_amdgcn_mfma_f32_16x16x32_bf16(e0, zf[r][0], ee, 0, 0, 0);
        a = __builtin_amdgcn_mfma_f32_16x16x32_bf16(e1, zf[r][1], a, 0, 0, 0);
        const unsigned t0 = (__float_as_uint(a[0]) & 0xFFFFFC00u) | kj0;
        const unsigned t1 = (__float_as_uint(a[1]) & 0xFFFFFC00u) | kj1;
        const unsigned t2k = (__float_as_uint(a[2]) & 0xFFFFFC00u) | kj2;
        const unsigned t3 = (__float_as_uint(a[3]) & 0xFFFFFC00u) | kj3;
        rk[r] = min(rk[r], min(min(min(t0, t1), t2k), t3) + g16);
      }
    }
    __builtin_amdgcn_s_setprio(0);
    // refill the buffer whose reads just retired (per-wave order + ds_read
    // latency << gld_lds writeback keeps this race-free without a barrier)
    if (ph < 6) STAGE(ph + 2, ph & 1);
  }
#undef STAGE

  // reduce keys across the 4 ksl lane groups; publish per-wave keys
#pragma unroll
  for (int r = 0; r < 4; ++r) {
    rk[r] = min(rk[r], (unsigned)__shfl_xor((int)rk[r], 16, 64));
    rk[r] = min(rk[r], (unsigned)__shfl_xor((int)rk[r], 32, 64));
  }
  if (ksl == 0) {
#pragma unroll
    for (int r = 0; r < 4; ++r) skey[wave][r * 16 + lr] = rk[r];
  }
  __syncthreads();   // the only block-wide barrier

  // epilogue (R1-proven): 4 threads per row; combine 4 wave-quarters,
  // gather z_q, write idx, loss/var partials.
  const int row = tid >> 2, seg = tid & 3;
  const unsigned k = min(min(skey[0][row], skey[1][row]),
                         min(skey[2][row], skey[3][row]));
  const unsigned idx = k & 1023u;
  const size_t rowg = (size_t)row_base + row;
  const f32x4* ep = (const f32x4*)(emb + (size_t)idx * 64 + seg * 16);
  f32x4* op = (f32x4*)(out + rowg * 64 + seg * 16);
#pragma unroll
  for (int c = 0; c < 4; ++c) op[c] = ep[c];

  float ls = 0.f; int s1 = 0, s2 = 0;
  if (seg == 0) {
    // d = ||z||^2 + (0.5 + ee - 2 z.e)_min - 0.5 ; low 10 bits were cleared
    ls = szz[row] + __uint_as_float(k & 0xFFFFFC00u) - 0.5f;
    s1 = (int)idx;
    s2 = (int)(idx * idx);
    out[OUT_IDX + rowg] = (float)idx;
  }
#pragma unroll
  for (int off = 1; off < 64; off <<= 1) {
    ls += __shfl_xor(ls, off, 64);
    s1 += __shfl_xor(s1, off, 64);
    s2 += __shfl_xor(s2, off, 64);
  }
  if (lane == 0) { sL[wave] = ls; sA[wave] = s1; sB[wave] = s2; }
  __syncthreads();
  if (tid == 0) {
    float L = 0; int a = 0, b = 0;
#pragma unroll
    for (int w = 0; w < 4; ++w) { L += sL[w]; a += sA[w]; b += sB[w]; }
    ((float*)(ws + WS_LOSS))[blockIdx.x] = L;
    ((int*)(ws + WS_S1))[blockIdx.x] = a;
    ((int*)(ws + WS_S2))[blockIdx.x] = b;
  }
}

// ---- K2: final scalar reduce over 2048 block partials ---------------------
__global__ void vq_final(float* __restrict__ out, const char* __restrict__ ws) {
  const int t = threadIdx.x;   // 256 threads
  const float* lp = (const float*)(ws + WS_LOSS);
  const int* p1 = (const int*)(ws + WS_S1);
  const int* p2 = (const int*)(ws + WS_S2);
  double L = 0; long long a = 0, b = 0;
#pragma unroll
  for (int kk = 0; kk < 8; ++kk) {
    const int i = t + 256 * kk;
    L += (double)lp[i];
    a += (long long)p1[i];
    b += (long long)p2[i];
  }
#pragma unroll
  for (int off = 1; off < 64; off <<= 1) {
    L += __shfl_xor(L, off, 64);
    a += __shfl_xor(a, off, 64);
    b += __shfl_xor(b, off, 64);
  }
  __shared__ double sLf[4];
  __shared__ long long sAf[4], sBf[4];
  const int wave = t >> 6, lane = t & 63;
  if (lane == 0) { sLf[wave] = L; sAf[wave] = a; sBf[wave] = b; }
  __syncthreads();
  if (t == 0) {
    double Lt = 0; long long at = 0, bt = 0;
#pragma unroll
    for (int w = 0; w < 4; ++w) { Lt += sLf[w]; at += sAf[w]; bt += sBf[w]; }
    // loss = (beta + 1) * mean((z_q - z)^2), beta = 0.25
    out[OUT_LOSS] = (float)(1.25 * Lt / 8388608.0);
    // var(idx, ddof=1) exact: (n*S2 - S1^2) / (n*(n-1))
    long long num = bt * 131072LL - at * at;
    out[OUT_VAR] = (float)((double)num / (131072.0 * 131071.0));
  }
}

extern "C" void kernel_launch(void* const* d_in, const int* in_sizes, int n_in,
                              void* d_out, int out_size, void* d_ws, size_t ws_size,
                              hipStream_t stream) {
  (void)in_sizes; (void)n_in; (void)out_size; (void)ws_size;
  const float* z = (const float*)d_in[0];
  const float* emb = (const float*)d_in[1];
  float* out = (float*)d_out;
  char* ws = (char*)d_ws;
  vq_prep<<<64, 64, 0, stream>>>(emb, ws);
  vq_main<<<2048, 256, 0, stream>>>(z, emb, out, ws);
  vq_final<<<1, 256, 0, stream>>>(out, ws);
}